// Round 1
// baseline (795.640 us; speedup 1.0000x reference)
//
#include <hip/hip_runtime.h>
#include <math.h>

// Problem constants
// B=4096, N=196, D=32, M=12, NH=4, DH=8, H=W=14
// outputs (flat f32): Z[4096*32] | A_maps[4096*12*196] | head_energy[4096*12*4] | S[4096*12*32] | topk_mass[4096*12]

__device__ __forceinline__ float wred_max(float v){
  #pragma unroll
  for (int off = 32; off; off >>= 1) v = fmaxf(v, __shfl_xor(v, off, 64));
  return v;
}
__device__ __forceinline__ float wred_sum(float v){
  #pragma unroll
  for (int off = 32; off; off >>= 1) v += __shfl_xor(v, off, 64);
  return v;
}
__device__ __forceinline__ float dot4(float4 a, float4 b){
  return a.x*b.x + a.y*b.y + a.z*b.z + a.w*b.w;
}

// ---------------- prologue: G = (Q Wq^T reshaped) * Wk / sqrt(8), rpbc gather ----------------
// ws layout (floats): G[1536] | rpbc[9408]
__global__ void prologue_kernel(const float* __restrict__ Q, const float* __restrict__ Wq,
                                const float* __restrict__ Wk, const float* __restrict__ rpb,
                                const float* __restrict__ qc, const float* __restrict__ kc,
                                float* __restrict__ ws)
{
  __shared__ float Qp[384];
  const int tid = threadIdx.x;
  for (int i = tid; i < 384; i += 256){
    int m = i >> 5, d = i & 31;
    float a = 0.f;
    #pragma unroll
    for (int c = 0; c < 32; ++c) a += Q[m*32+c] * Wq[d*32+c];
    Qp[i] = a;
  }
  __syncthreads();
  float* G = ws;
  float* rpbc = ws + 1536;
  const float s = 0.35355339059327373f; // 1/sqrt(8)
  for (int i = tid; i < 1536; i += 256){
    int hm = i >> 5, c = i & 31;
    int h = hm / 12, m = hm - 12*h;
    float a = 0.f;
    #pragma unroll
    for (int dh = 0; dh < 8; ++dh) a += Qp[m*32 + h*8 + dh] * Wk[(h*8+dh)*32 + c];
    G[i] = a * s;
  }
  for (int i = tid; i < 9408; i += 256){
    int hm = i / 196, n = i - 196*hm;
    int h = hm / 12, m = hm - 12*h;
    float dy = qc[2*m]   - kc[2*n];
    float dx = qc[2*m+1] - kc[2*n+1];
    int iy = (int)rintf(dy) + 13; iy = iy < 0 ? 0 : (iy > 26 ? 26 : iy);
    int ix = (int)rintf(dx) + 13; ix = ix < 0 ? 0 : (ix > 26 ? 26 : ix);
    rpbc[i] = rpb[h*729 + iy*27 + ix];
  }
}

// ---------------- main fused kernel: one block per batch element ----------------
__global__ __launch_bounds__(256, 2) void slotpool_main(
    const float* __restrict__ T, const float* __restrict__ Wv, const float* __restrict__ Wp,
    const float* __restrict__ bp, const float* __restrict__ ws, float* __restrict__ out)
{
  __shared__ __align__(16) float Ts[196*36];   // T rows, padded stride 36
  __shared__ __align__(16) float As[48*196];   // A[h*12+m][n]
  __shared__ __align__(16) float GU[1536];     // G then (reused) U
  __shared__ __align__(16) float Ss[384];      // S for this b (m*32+d)
  __shared__ float red[256];

  const int b    = blockIdx.x;
  const int tid  = threadIdx.x;
  const int lane = tid & 63;
  const int h    = tid >> 6;   // wave id == head in step B

  float* outZ = out;                       // [4096][32]
  float* outA = out + 131072;              // [4096][12][196]
  float* outE = out + 9764864;             // [4096][12][4]
  float* outS = out + 9961472;             // [4096][12][32]
  float* outK = out + 11534336;            // [4096][12]

  const float* G    = ws;
  const float* rpbc = ws + 1536;

  // ---- A: stage T (row-major, padded) and G into LDS ----
  const float4* Tg = (const float4*)(T + (size_t)b * 6272);
  for (int i = tid; i < 1568; i += 256){
    int n = i >> 3, c4 = i & 7;
    *(float4*)&Ts[n*36 + c4*4] = Tg[i];
  }
  for (int i = tid; i < 384; i += 256) ((float4*)GU)[i] = ((const float4*)G)[i];
  __syncthreads();

  // ---- B: content (T @ G^T) + rpb, softmax over n, entropy ----
  const int n0 = lane, n1 = lane + 64, n2 = lane + 128, n3 = lane + 192;
  const bool v3 = (n3 < 196);
  const int n3c = v3 ? n3 : 195;

  float acc[12][4];
  #pragma unroll
  for (int m = 0; m < 12; ++m){
    const float* rrow = rpbc + (h*12 + m) * 196;
    acc[m][0] = rrow[n0]; acc[m][1] = rrow[n1];
    acc[m][2] = rrow[n2]; acc[m][3] = rrow[n3c];
  }
  #pragma unroll
  for (int c4 = 0; c4 < 8; ++c4){
    float4 t0 = *(const float4*)&Ts[n0 *36 + c4*4];
    float4 t1 = *(const float4*)&Ts[n1 *36 + c4*4];
    float4 t2 = *(const float4*)&Ts[n2 *36 + c4*4];
    float4 t3 = *(const float4*)&Ts[n3c*36 + c4*4];
    #pragma unroll
    for (int m = 0; m < 12; ++m){
      float4 g = *(const float4*)&GU[(h*12 + m)*32 + c4*4];
      acc[m][0] += dot4(t0, g);
      acc[m][1] += dot4(t1, g);
      acc[m][2] += dot4(t2, g);
      acc[m][3] += dot4(t3, g);
    }
  }
  const float LOGN_INV = 0.18946127f; // 1/ln(196)
  #pragma unroll
  for (int m = 0; m < 12; ++m){
    float x0 = acc[m][0], x1 = acc[m][1], x2 = acc[m][2];
    float x3 = v3 ? acc[m][3] : -__builtin_inff();
    float mx = wred_max(fmaxf(fmaxf(x0, x1), fmaxf(x2, x3)));
    float e0 = __expf(x0 - mx), e1 = __expf(x1 - mx), e2 = __expf(x2 - mx);
    float e3 = v3 ? __expf(x3 - mx) : 0.f;
    float s  = wred_sum(e0 + e1 + e2 + e3);
    float t  = wred_sum((x0-mx)*e0 + (x1-mx)*e1 + (x2-mx)*e2 + (v3 ? (x3-mx)*e3 : 0.f));
    float inv = 1.f / s;
    float* arow = As + (h*12 + m) * 196;
    arow[n0] = e0 * inv; arow[n1] = e1 * inv; arow[n2] = e2 * inv;
    if (v3) arow[n3] = e3 * inv;
    if (lane == 0)
      outE[(size_t)b*48 + m*4 + h] = 1.0f + (t*inv - __logf(s)) * LOGN_INV;
  }
  __syncthreads();

  // ---- C: A_avg over heads, A_maps out, top-9 mass ----
  #pragma unroll
  for (int mi = 0; mi < 3; ++mi){
    int m = h + mi*4;
    float av[4];
    av[0] = 0.25f*(As[m*196+n0] + As[(12+m)*196+n0] + As[(24+m)*196+n0] + As[(36+m)*196+n0]);
    av[1] = 0.25f*(As[m*196+n1] + As[(12+m)*196+n1] + As[(24+m)*196+n1] + As[(36+m)*196+n1]);
    av[2] = 0.25f*(As[m*196+n2] + As[(12+m)*196+n2] + As[(24+m)*196+n2] + As[(36+m)*196+n2]);
    av[3] = 0.25f*(As[m*196+n3c] + As[(12+m)*196+n3c] + As[(24+m)*196+n3c] + As[(36+m)*196+n3c]);
    float* amrow = outA + (size_t)b*2352 + m*196;
    amrow[n0] = av[0]; amrow[n1] = av[1]; amrow[n2] = av[2];
    if (v3) amrow[n3] = av[3]; else av[3] = -1.f;

    float mass = 0.f;
    for (int k = 0; k < 9; ++k){
      float l = fmaxf(fmaxf(av[0], av[1]), fmaxf(av[2], av[3]));
      float g = wred_max(l);
      mass += g;
      int slot = (av[0]==g) ? 0 : ((av[1]==g) ? 1 : ((av[2]==g) ? 2 : ((av[3]==g) ? 3 : -1)));
      unsigned long long ball = __ballot(slot >= 0);
      if (ball){
        int leader = __ffsll(ball) - 1;
        if (lane == leader){
          if      (slot == 0) av[0] = -2.f;
          else if (slot == 1) av[1] = -2.f;
          else if (slot == 2) av[2] = -2.f;
          else                av[3] = -2.f;
        }
      }
    }
    if (lane == 0) outK[(size_t)b*12 + m] = mass;
  }

  // ---- D: U[mh][c] = sum_n A[mh][n] * T[n][c]   (overwrites GU; G is dead) ----
  {
    const int c4  = tid & 7;
    const int mh0 = tid >> 3;  // 0..31
    #pragma unroll
    for (int k = 0; k < 2; ++k){
      int mh = mh0 + 32*k;
      if (mh < 48){
        const float4* Arow = (const float4*)(As + mh*196);
        float4 u = {0.f, 0.f, 0.f, 0.f};
        for (int q = 0; q < 49; ++q){
          float4 a = Arow[q];
          const float* tb = &Ts[(4*q)*36 + c4*4];
          float4 p0 = *(const float4*)(tb);
          float4 p1 = *(const float4*)(tb + 36);
          float4 p2 = *(const float4*)(tb + 72);
          float4 p3 = *(const float4*)(tb + 108);
          u.x += a.x*p0.x + a.y*p1.x + a.z*p2.x + a.w*p3.x;
          u.y += a.x*p0.y + a.y*p1.y + a.z*p2.y + a.w*p3.y;
          u.z += a.x*p0.z + a.y*p1.z + a.z*p2.z + a.w*p3.z;
          u.w += a.x*p0.w + a.y*p1.w + a.z*p2.w + a.w*p3.w;
        }
        *(float4*)&GU[mh*32 + c4*4] = u;
      }
    }
  }
  __syncthreads();

  // ---- E: S[m][d] = sum_c U[(d>>3)*12+m][c] * Wv[d][c]; write S out ----
  for (int md = tid; md < 384; md += 256){
    int m = md >> 5, d = md & 31, hh = d >> 3;
    const float4* Urow = (const float4*)(GU + (hh*12 + m)*32);
    const float4* Wvr  = (const float4*)(Wv + d*32);
    float a = 0.f;
    #pragma unroll
    for (int q = 0; q < 8; ++q) a += dot4(Urow[q], Wvr[q]);
    Ss[md] = a;
    outS[(size_t)b*384 + md] = a;
  }
  __syncthreads();

  // ---- F: Z[d] = bp[d] + sum_j Wp[d][j] * Ss[j] ----
  {
    int d = tid >> 3, jb = tid & 7;
    float a = 0.f;
    #pragma unroll
    for (int jj = 0; jj < 48; ++jj){
      int j = jb + jj*8;
      a += Wp[d*384 + j] * Ss[j];
    }
    red[tid] = a;
  }
  __syncthreads();
  if (tid < 32){
    float a = bp[tid];
    #pragma unroll
    for (int k = 0; k < 8; ++k) a += red[tid*8 + k];
    outZ[(size_t)b*32 + tid] = a;
  }
}

extern "C" void kernel_launch(void* const* d_in, const int* in_sizes, int n_in,
                              void* d_out, int out_size, void* d_ws, size_t ws_size,
                              hipStream_t stream)
{
  const float* T    = (const float*)d_in[0];
  const float* Q    = (const float*)d_in[1];
  const float* Wq   = (const float*)d_in[2];
  const float* Wk   = (const float*)d_in[3];
  const float* Wv   = (const float*)d_in[4];
  const float* Wp   = (const float*)d_in[5];
  const float* bp   = (const float*)d_in[6];
  const float* rpb  = (const float*)d_in[7];
  const float* qc   = (const float*)d_in[8];
  const float* kc   = (const float*)d_in[9];
  float* ws  = (float*)d_ws;
  float* outp = (float*)d_out;

  prologue_kernel<<<1, 256, 0, stream>>>(Q, Wq, Wk, rpb, qc, kc, ws);
  slotpool_main<<<4096, 256, 0, stream>>>(T, Wv, Wp, bp, ws, outp);
}